// Round 4
// baseline (529.182 us; speedup 1.0000x reference)
//
#include <hip/hip_runtime.h>
#include <stdint.h>

// GCN pipeline on MI355X. Factorization:
//   (m/deg)@msg = diag(rsqrt(rd)) * m_bf16 @ (diag(rsqrt(cd))*msg)
// R7: k_gemm BK 64->128 (8 barrier rounds/block; drain-count lever measured
// -16us at 32->16 rounds in R6). XOR swizzle for 256B rows: slot s of row r
// holds chunk s^(r&7), staged via pre-swizzled global addrs (even/odd jj ptr
// pair). k_castcd 8 rows/block (grid 1024, 2x blocks/CU). k_wprep pre-casts
// w1/w2 to bf16 so k_msg's A-fragments are single 16B loads.
//   k_wprep    : w1,w2 fp32 -> bf16
//   k_castcd   : m fp32 -> mb bf16, rd row sums, cdpart col partials (1024 slabs)
//   k_cd2      : reduce 1024 slabs -> cd
//   k_msg      : msgT[n][j] = bf16(relu(src[j]@W[n]+b[n]) * rsqrt(cd[j]))  (MFMA)
//   k_gemm     : split-K=8 bf16 MFMA GEMM, BK=128, global_load_lds w16
//   k_red      : h[i][:] = rsqrt(rd[i]) * sum_p part[p][i][:]   (coalesced)
//   k_poolcls  : per-graph max over h + 16-class linear

#define NN 8192
#define DH 128
#define NCLS 16
#define NGRAPH 64
#define SPLITK 8
#define KCHUNK (NN / SPLITK) // 1024

typedef float floatx4 __attribute__((ext_vector_type(4)));
typedef __bf16 bf16x8 __attribute__((ext_vector_type(8)));

__device__ __forceinline__ unsigned f2bf_bits(float f) {
    union { float f; unsigned u; } v; v.f = f;
    unsigned u = v.u;
    u += 0x7fffu + ((u >> 16) & 1u);   // RNE
    return u >> 16;
}

__device__ __forceinline__ void gload16(const void* g, void* l) {
    __builtin_amdgcn_global_load_lds(
        (const __attribute__((address_space(1))) void*)g,
        (__attribute__((address_space(3))) void*)l, 16, 0, 0);
}

// ---- w1,w2 fp32 -> bf16. 32768 elems total, grid 32 x 256 thr x 4 elems.
__global__ __launch_bounds__(256) void k_wprep(
    const float* __restrict__ w1, const float* __restrict__ w2,
    unsigned short* __restrict__ wb)
{
    int idx = (blockIdx.x * 256 + threadIdx.x) * 4;
    const float* src = (idx < 16384) ? (w1 + idx) : (w2 + idx - 16384);
    float4 a = *(const float4*)src;
    uint2 o;
    o.x = f2bf_bits(a.x) | (f2bf_bits(a.y) << 16);
    o.y = f2bf_bits(a.z) | (f2bf_bits(a.w) << 16);
    *(uint2*)(wb + idx) = o;
}

// ---- m fp32 -> mb bf16, rd row sums, col partial sums. Block = 8 rows.
__global__ __launch_bounds__(256) void k_castcd(
    const float* __restrict__ m, unsigned short* __restrict__ mb,
    float* __restrict__ rd, float* __restrict__ cdpart)
{
    __shared__ float red[256][9];
    int t = threadIdx.x;
    int rb = blockIdx.x;             // rows rb*8 .. +7
    float cs[32];
#pragma unroll
    for (int u = 0; u < 32; ++u) cs[u] = 0.f;

    for (int r = 0; r < 8; ++r) {
        const float* src = m + ((size_t)rb * 8 + r) * NN;
        unsigned short* dst = mb + ((size_t)rb * 8 + r) * NN;
        float rsum = 0.f;
#pragma unroll
        for (int it = 0; it < 8; ++it) {
            int c = it * 1024 + t * 4;
            float4 a = *(const float4*)(src + c);
            rsum += (a.x + a.y) + (a.z + a.w);
            cs[it * 4 + 0] += a.x; cs[it * 4 + 1] += a.y;
            cs[it * 4 + 2] += a.z; cs[it * 4 + 3] += a.w;
            uint2 o;
            o.x = f2bf_bits(a.x) | (f2bf_bits(a.y) << 16);
            o.y = f2bf_bits(a.z) | (f2bf_bits(a.w) << 16);
            *(uint2*)(dst + c) = o;
        }
        red[t][r] = rsum;
    }
#pragma unroll
    for (int it = 0; it < 8; ++it) {
        float4 o = (float4){cs[it * 4], cs[it * 4 + 1], cs[it * 4 + 2], cs[it * 4 + 3]};
        *(float4*)(cdpart + (size_t)rb * NN + it * 1024 + t * 4) = o;
    }
    __syncthreads();
    if (t < 8) {
        float s = 0.f;
#pragma unroll 8
        for (int u = 0; u < 256; ++u) s += red[u][t];
        rd[rb * 8 + t] = s;
    }
}

// ---- reduce 1024 col-partial slabs -> cd. Block owns 32 cols, 8 slab groups.
__global__ __launch_bounds__(256) void k_cd2(
    const float* __restrict__ cdpart, float* __restrict__ cd)
{
    __shared__ float p2[8][33];
    int c = threadIdx.x & 31, g = threadIdx.x >> 5;
    int col = blockIdx.x * 32 + c;
    float s = 0.f;
#pragma unroll 8
    for (int r = 0; r < 128; ++r)
        s += cdpart[(size_t)(g * 128 + r) * NN + col];
    p2[g][c] = s;
    __syncthreads();
    if (threadIdx.x < 32) {
        float a = 0.f;
#pragma unroll
        for (int u = 0; u < 8; ++u) a += p2[u][threadIdx.x];
        cd[blockIdx.x * 32 + threadIdx.x] = a;
    }
}

// ---- msgT[n][j] = bf16( relu( src[j]@W[n] + b[n] ) * rsqrt(cd[j]) )
// Weights pre-cast to bf16 (wb). 2 waves/block, wave wv owns tiles wv*4..+3.
__global__ __launch_bounds__(128) void k_msg(
    const int* __restrict__ x, const float* __restrict__ emb,
    const float* __restrict__ hsrc,
    const unsigned short* __restrict__ wb, const float* __restrict__ bias,
    const float* __restrict__ cdv, unsigned short* __restrict__ msgT,
    int layer)
{
    int wv = threadIdx.x >> 6;
    int lane = threadIdx.x & 63;
    int quad = lane >> 4, r16 = lane & 15;
    int j = blockIdx.x * 16 + r16;

    floatx4 acc[4];
#pragma unroll
    for (int t = 0; t < 4; ++t) acc[t] = (floatx4)0.f;

    const float* src;
    if (layer == 1) src = emb + (size_t)x[j] * DH;
    else            src = hsrc + (size_t)j * DH;

#pragma unroll
    for (int e0 = 0; e0 < DH; e0 += 32) {
        int ke = e0 + quad * 8;
        float4 a = *(const float4*)(src + ke);
        float4 b = *(const float4*)(src + ke + 4);
        bf16x8 bfv;
        bfv[0] = (__bf16)a.x; bfv[1] = (__bf16)a.y; bfv[2] = (__bf16)a.z; bfv[3] = (__bf16)a.w;
        bfv[4] = (__bf16)b.x; bfv[5] = (__bf16)b.y; bfv[6] = (__bf16)b.z; bfv[7] = (__bf16)b.w;
#pragma unroll
        for (int tt = 0; tt < 4; ++tt) {
            int t = wv * 4 + tt;
            bf16x8 af = *(const bf16x8*)(wb + (size_t)(t * 16 + r16) * DH + ke);
            acc[tt] = __builtin_amdgcn_mfma_f32_16x16x32_bf16(af, bfv, acc[tt], 0, 0, 0);
        }
    }
    float cs = rsqrtf(cdv[j]);
#pragma unroll
    for (int tt = 0; tt < 4; ++tt) {
#pragma unroll
        for (int r = 0; r < 4; ++r) {
            int n = (wv * 4 + tt) * 16 + quad * 4 + r;
            float val = acc[tt][r] + bias[n];
            val = fmaxf(val, 0.f) * cs;
            msgT[(size_t)n * NN + j] = (unsigned short)f2bf_bits(val);
        }
    }
}

// ---- part[kp][i][n] = sum_{k in chunk kp} A[i][k] * Bt[n][k]
// BM=128, BN=128, BK=128, 4 waves of 64x64. 8 stage+drain rounds per block.
// LDS tile [128 rows][256 B]; slot s of row r holds global chunk s^(r&7)
// (staged via pre-swizzled global addrs; LDS dest linear per rule #21).
__global__ __launch_bounds__(256) void k_gemm(
    const unsigned short* __restrict__ A,   // 8192 x 8192 bf16 row-major
    const unsigned short* __restrict__ Bt,  // 128 x 8192 bf16 (N x K)
    float* __restrict__ part)               // SPLITK x 8192 x 128
{
    __shared__ unsigned short lA[128 * 128];  // 32 KB
    __shared__ unsigned short lB[128 * 128];  // 32 KB
    int mblk = blockIdx.x & 63;
    int kp = blockIdx.x >> 6;
    int tid = threadIdx.x;
    int wv = tid >> 6, lane = tid & 63;
    int quad = lane >> 4, r16 = lane & 15;
    int wm = wv >> 1, wn = wv & 1;
    size_t mbase = (size_t)mblk * 128;
    int kbase = kp * KCHUNK;

    floatx4 acc[4][4];
#pragma unroll
    for (int mi = 0; mi < 4; ++mi)
#pragma unroll
        for (int ni = 0; ni < 4; ++ni) acc[mi][ni] = (floatx4)0.f;

    // staging: each gload16 covers 4 rows x 256B. lane = srow2*16 + slot.
    // LDS slot written = slot; global chunk fetched = slot ^ (row&7) where
    // row = wv*32 + jj*4 + srow2, so (row&7) = srow2 ^ (4*(jj&1)).
    int srow2 = lane >> 4;           // 0..3
    int slot = lane & 15;            // 0..15
    int q0 = slot ^ srow2;           // chunk for even jj
    int q1 = q0 ^ 4;                 // chunk for odd jj
    const unsigned short* gAe = A + (mbase + wv * 32 + srow2) * (size_t)NN + kbase + q0 * 8;
    const unsigned short* gAo = A + (mbase + wv * 32 + srow2) * (size_t)NN + kbase + q1 * 8;
    const unsigned short* gBe = Bt + (size_t)(wv * 32 + srow2) * NN + kbase + q0 * 8;
    const unsigned short* gBo = Bt + (size_t)(wv * 32 + srow2) * NN + kbase + q1 * 8;
    char* lAw = (char*)lA + wv * 8192;
    char* lBw = (char*)lB + wv * 8192;

    for (int it = 0; it < KCHUNK / 128; ++it) {   // 8 rounds
#pragma unroll
        for (int jj = 0; jj < 8; ++jj) {
            const unsigned short* pA = (jj & 1) ? gAo : gAe;
            const unsigned short* pB = (jj & 1) ? gBo : gBe;
            gload16(pA + (size_t)(4 * jj) * NN, lAw + jj * 1024);
            gload16(pB + (size_t)(4 * jj) * NN, lBw + jj * 1024);
        }
        __syncthreads();
#pragma unroll
        for (int ks = 0; ks < 4; ++ks) {
            bf16x8 af[4], bf[4];
#pragma unroll
            for (int mi = 0; mi < 4; ++mi) {
                int row = wm * 64 + mi * 16 + r16;
                int ch = (ks * 4 + quad) ^ (r16 & 7);
                af[mi] = *(const bf16x8*)((const char*)lA + (row * 256 + ch * 16));
            }
#pragma unroll
            for (int ni = 0; ni < 4; ++ni) {
                int row = wn * 64 + ni * 16 + r16;
                int ch = (ks * 4 + quad) ^ (r16 & 7);
                bf[ni] = *(const bf16x8*)((const char*)lB + (row * 256 + ch * 16));
            }
#pragma unroll
            for (int mi = 0; mi < 4; ++mi)
#pragma unroll
                for (int ni = 0; ni < 4; ++ni)
                    acc[mi][ni] = __builtin_amdgcn_mfma_f32_16x16x32_bf16(af[mi], bf[ni], acc[mi][ni], 0, 0, 0);
        }
        __syncthreads();
        gAe += 128; gAo += 128; gBe += 128; gBo += 128;
    }

    float* outp = part + (size_t)kp * ((size_t)NN * DH);
#pragma unroll
    for (int mi = 0; mi < 4; ++mi) {
#pragma unroll
        for (int r = 0; r < 4; ++r) {
            size_t i = mbase + wm * 64 + mi * 16 + quad * 4 + r;
            float* op = outp + i * DH + wn * 64 + r16;
#pragma unroll
            for (int ni = 0; ni < 4; ++ni) op[ni * 16] = acc[mi][ni][r];
        }
    }
}

// ---- h[i][c] = rsqrt(rd[i]) * sum_p part[p][i][c]. Coalesced float4.
__global__ __launch_bounds__(256) void k_red(
    const float* __restrict__ part, const float* __restrict__ rdv,
    float* __restrict__ h)
{
    int i = blockIdx.x * 8 + (threadIdx.x >> 5);
    int c4 = (threadIdx.x & 31) * 4;
    size_t off = (size_t)i * DH + c4;
    float4 s = (float4){0.f, 0.f, 0.f, 0.f};
#pragma unroll
    for (int p = 0; p < SPLITK; ++p) {
        float4 v = *(const float4*)(part + (size_t)p * ((size_t)NN * DH) + off);
        s.x += v.x; s.y += v.y; s.z += v.z; s.w += v.w;
    }
    float sc = rsqrtf(rdv[i]);
    s.x *= sc; s.y *= sc; s.z *= sc; s.w *= sc;
    *(float4*)(h + off) = s;
}

// ---- per-graph max over 128 rows of h + 16-class linear. grid 64.
__global__ __launch_bounds__(256) void k_poolcls(
    const float* __restrict__ h, const float* __restrict__ wc,
    const float* __restrict__ bc, float* __restrict__ out)
{
    __shared__ float red[256];
    __shared__ float pooled[128];
    int g = blockIdx.x;
    int c = threadIdx.x & 127, rh = threadIdx.x >> 7;
    float mx = -1e30f;
#pragma unroll 8
    for (int r = 0; r < 64; ++r) {
        int i = g * 128 + rh * 64 + r;
        mx = fmaxf(mx, h[(size_t)i * DH + c]);
    }
    red[threadIdx.x] = mx;
    __syncthreads();
    if (rh == 0) pooled[c] = fmaxf(red[c], red[c + 128]);
    __syncthreads();
    if (threadIdx.x < NCLS) {
        float a = bc[threadIdx.x];
        const float* wr = wc + threadIdx.x * 128;
#pragma unroll 8
        for (int k = 0; k < 128; ++k) a += pooled[k] * wr[k];
        out[g * NCLS + threadIdx.x] = a;
    }
}

extern "C" void kernel_launch(void* const* d_in, const int* in_sizes, int n_in,
                              void* d_out, int out_size, void* d_ws, size_t ws_size,
                              hipStream_t stream)
{
    const int*   x   = (const int*)  d_in[0];
    const float* m   = (const float*)d_in[1];
    // d_in[2] = bm: (i*64)//8192 -> 128 consecutive rows per graph (fixed by setup)
    const float* emb = (const float*)d_in[3];
    const float* w1  = (const float*)d_in[4];
    const float* b1  = (const float*)d_in[5];
    const float* w2  = (const float*)d_in[6];
    const float* b2  = (const float*)d_in[7];
    const float* wc  = (const float*)d_in[8];
    const float* bc  = (const float*)d_in[9];
    float* out = (float*)d_out;

    char* ws = (char*)d_ws;
    unsigned short* mb = (unsigned short*)ws;                         // 128 MB
    float* rd   = (float*)(ws + (size_t)134217728);                   // 32 KB
    float* cd   = rd + NN;                                            // 32 KB
    unsigned short* msgT = (unsigned short*)(cd + NN);                // 2 MB
    float* part = (float*)((char*)msgT + (size_t)2 * NN * DH);        // 32 MB
    float* cdpart = part;      // aliased (32 MB): consumed before first k_gemm
    float* h    = part + (size_t)SPLITK * NN * DH;                    // 4 MB
    unsigned short* wb = (unsigned short*)(h + (size_t)NN * DH);      // 64 KB (wb1|wb2)

    k_wprep<<<32, 256, 0, stream>>>(w1, w2, wb);
    k_castcd<<<NN / 8, 256, 0, stream>>>(m, mb, rd, cdpart);
    k_cd2<<<NN / 32, 256, 0, stream>>>(cdpart, cd);
    k_msg<<<NN / 16, 128, 0, stream>>>(x, emb, nullptr, wb, b1, cd, msgT, 1);
    k_gemm<<<64 * SPLITK, 256, 0, stream>>>(mb, msgT, part);
    k_red<<<NN / 8, 256, 0, stream>>>(part, rd, h);
    k_msg<<<NN / 16, 128, 0, stream>>>(nullptr, nullptr, h, wb + 16384, b2, cd, msgT, 2);
    k_gemm<<<64 * SPLITK, 256, 0, stream>>>(mb, msgT, part);
    k_red<<<NN / 8, 256, 0, stream>>>(part, rd, h);
    k_poolcls<<<NGRAPH, 256, 0, stream>>>(h, wc, bc, out);
}